// Round 1
// baseline (316.649 us; speedup 1.0000x reference)
//
#include <hip/hip_runtime.h>

// Problem constants (from reference setup_inputs)
#define B_ 2
#define D_ 160
#define H_ 192
#define W_ 160

constexpr long long HW_  = (long long)H_ * W_;
constexpr long long DHW_ = (long long)D_ * HW_;

__device__ __forceinline__ float fetch_zero(const float* __restrict__ s, int z, int y, int x) {
    // zeros padding: out-of-bounds taps contribute 0
    if ((unsigned)z < (unsigned)D_ && (unsigned)y < (unsigned)H_ && (unsigned)x < (unsigned)W_)
        return s[(long long)z * HW_ + (long long)y * W_ + x];
    return 0.0f;
}

__device__ __forceinline__ float trilerp(const float* __restrict__ s, float z, float y, float x) {
    float zf = floorf(z), yf = floorf(y), xf = floorf(x);
    int z0 = (int)zf, y0 = (int)yf, x0 = (int)xf;
    float wz1 = z - zf, wy1 = y - yf, wx1 = x - xf;
    float wz0 = 1.0f - wz1, wy0 = 1.0f - wy1, wx0 = 1.0f - wx1;
    float v000 = fetch_zero(s, z0,     y0,     x0);
    float v001 = fetch_zero(s, z0,     y0,     x0 + 1);
    float v010 = fetch_zero(s, z0,     y0 + 1, x0);
    float v011 = fetch_zero(s, z0,     y0 + 1, x0 + 1);
    float v100 = fetch_zero(s, z0 + 1, y0,     x0);
    float v101 = fetch_zero(s, z0 + 1, y0,     x0 + 1);
    float v110 = fetch_zero(s, z0 + 1, y0 + 1, x0);
    float v111 = fetch_zero(s, z0 + 1, y0 + 1, x0 + 1);
    return ((v000 * wx0 + v001 * wx1) * wy0 + (v010 * wx0 + v011 * wx1) * wy1) * wz0
         + ((v100 * wx0 + v101 * wx1) * wy0 + (v110 * wx0 + v111 * wx1) * wy1) * wz1;
}

__global__ __launch_bounds__(256) void st3d_kernel(const float* __restrict__ src,
                                                   const float* __restrict__ flow,
                                                   float* __restrict__ out) {
    // Collapsed coordinate transform: z = (idz + flow_z) * D/(D-1) - 0.5
    const float SZ = (float)D_ / (float)(D_ - 1);
    const float SY = (float)H_ / (float)(H_ - 1);
    const float SX = (float)W_ / (float)(W_ - 1);

    long long i = (long long)blockIdx.x * blockDim.x + threadIdx.x; // unit: 4 voxels
    const long long n4 = (long long)B_ * DHW_ / 4;
    if (i >= n4) return;

    long long s4 = i * 4;                 // flat voxel index within [B, DHW]
    int b = (int)(s4 / DHW_);
    long long s = s4 - (long long)b * DHW_;
    int w = (int)(s % W_);
    int h = (int)((s / W_) % H_);
    int d = (int)(s / HW_);

    const float* __restrict__ fb = flow + (long long)b * 3 * DHW_;
    float4 fz = *(const float4*)(fb + s);
    float4 fy = *(const float4*)(fb + DHW_ + s);
    float4 fx = *(const float4*)(fb + 2 * DHW_ + s);

    const float* __restrict__ sp = src + (long long)b * DHW_; // C == 1

    float4 o;
    o.x = trilerp(sp, (d + fz.x) * SZ - 0.5f, (h + fy.x) * SY - 0.5f, (w + 0 + fx.x) * SX - 0.5f);
    o.y = trilerp(sp, (d + fz.y) * SZ - 0.5f, (h + fy.y) * SY - 0.5f, (w + 1 + fx.y) * SX - 0.5f);
    o.z = trilerp(sp, (d + fz.z) * SZ - 0.5f, (h + fy.z) * SY - 0.5f, (w + 2 + fx.z) * SX - 0.5f);
    o.w = trilerp(sp, (d + fz.w) * SZ - 0.5f, (h + fy.w) * SY - 0.5f, (w + 3 + fx.w) * SX - 0.5f);

    *(float4*)(out + (long long)b * DHW_ + s) = o;
}

extern "C" void kernel_launch(void* const* d_in, const int* in_sizes, int n_in,
                              void* d_out, int out_size, void* d_ws, size_t ws_size,
                              hipStream_t stream) {
    const float* src  = (const float*)d_in[0];
    const float* flow = (const float*)d_in[1];
    float* out = (float*)d_out;

    const long long n4 = (long long)B_ * DHW_ / 4; // 2,457,600 threads
    const int block = 256;
    const int grid = (int)((n4 + block - 1) / block); // 9600 blocks
    st3d_kernel<<<grid, block, 0, stream>>>(src, flow, out);
}

// Round 2
// 254.784 us; speedup vs baseline: 1.2428x; 1.2428x over previous
//
#include <hip/hip_runtime.h>

// Problem constants (from reference setup_inputs)
#define B_ 2
#define D_ 160
#define H_ 192
#define W_ 160

constexpr int HW_  = H_ * W_;          // 30720
constexpr int DHW_ = D_ * HW_;         // 4915200

__global__ __launch_bounds__(256) void st3d_kernel(const float* __restrict__ src,
                                                   const float* __restrict__ flow,
                                                   float* __restrict__ out) {
    // Collapsed coordinate transform: z = (idz + flow_z) * D/(D-1) - 0.5
    const float SZ = (float)D_ / (float)(D_ - 1);
    const float SY = (float)H_ / (float)(H_ - 1);
    const float SX = (float)W_ / (float)(W_ - 1);

    const int s = blockIdx.x * 256 + threadIdx.x;   // voxel index within one batch
    const int b = blockIdx.y;

    const int w = s % W_;
    const int t = s / W_;
    const int h = t % H_;
    const int d = t / H_;

    const float* __restrict__ fb = flow + (size_t)b * 3 * DHW_;
    const float fz = fb[s];
    const float fy = fb[DHW_ + s];
    const float fx = fb[2 * DHW_ + s];

    const float z = (d + fz) * SZ - 0.5f;
    const float y = (h + fy) * SY - 0.5f;
    const float x = (w + fx) * SX - 0.5f;

    const float zf = floorf(z), yf = floorf(y), xf = floorf(x);
    const int z0 = (int)zf, y0 = (int)yf, x0 = (int)xf;
    const int z1 = z0 + 1, y1 = y0 + 1, x1 = x0 + 1;

    float wz1 = z - zf, wy1 = y - yf, wx1 = x - xf;
    float wz0 = 1.0f - wz1, wy0 = 1.0f - wy1, wx0 = 1.0f - wx1;

    // Fold zeros-padding into the weights; clamp indices so loads are unconditional.
    wz0 = ((unsigned)z0 < (unsigned)D_) ? wz0 : 0.0f;
    wz1 = ((unsigned)z1 < (unsigned)D_) ? wz1 : 0.0f;
    wy0 = ((unsigned)y0 < (unsigned)H_) ? wy0 : 0.0f;
    wy1 = ((unsigned)y1 < (unsigned)H_) ? wy1 : 0.0f;
    wx0 = ((unsigned)x0 < (unsigned)W_) ? wx0 : 0.0f;
    wx1 = ((unsigned)x1 < (unsigned)W_) ? wx1 : 0.0f;

    const int z0c = min(max(z0, 0), D_ - 1), z1c = min(max(z1, 0), D_ - 1);
    const int y0c = min(max(y0, 0), H_ - 1), y1c = min(max(y1, 0), H_ - 1);
    const int x0c = min(max(x0, 0), W_ - 1), x1c = min(max(x1, 0), W_ - 1);

    const float* __restrict__ sp = src + (size_t)b * DHW_;  // C == 1
    const float* p00 = sp + z0c * HW_ + y0c * W_;
    const float* p01 = sp + z0c * HW_ + y1c * W_;
    const float* p10 = sp + z1c * HW_ + y0c * W_;
    const float* p11 = sp + z1c * HW_ + y1c * W_;

    // 8 unconditional loads — full MLP, near-coalesced across the wave.
    const float v000 = p00[x0c], v001 = p00[x1c];
    const float v010 = p01[x0c], v011 = p01[x1c];
    const float v100 = p10[x0c], v101 = p10[x1c];
    const float v110 = p11[x0c], v111 = p11[x1c];

    const float r = ((v000 * wx0 + v001 * wx1) * wy0 + (v010 * wx0 + v011 * wx1) * wy1) * wz0
                  + ((v100 * wx0 + v101 * wx1) * wy0 + (v110 * wx0 + v111 * wx1) * wy1) * wz1;

    out[(size_t)b * DHW_ + s] = r;
}

extern "C" void kernel_launch(void* const* d_in, const int* in_sizes, int n_in,
                              void* d_out, int out_size, void* d_ws, size_t ws_size,
                              hipStream_t stream) {
    const float* src  = (const float*)d_in[0];
    const float* flow = (const float*)d_in[1];
    float* out = (float*)d_out;

    dim3 grid(DHW_ / 256, B_);   // 19200 x 2 blocks, exact cover
    st3d_kernel<<<grid, dim3(256), 0, stream>>>(src, flow, out);
}

// Round 3
// 254.441 us; speedup vs baseline: 1.2445x; 1.0013x over previous
//
#include <hip/hip_runtime.h>

// Problem constants (from reference setup_inputs)
#define B_ 2
#define D_ 160
#define H_ 192
#define W_ 160

constexpr int HW_  = H_ * W_;          // 30720
constexpr int DHW_ = D_ * HW_;         // 4915200

// Output tile per block (256 threads, 8 voxels/thread)
#define TX 32
#define TY 8
#define TZ 8
#define HLO 4                          // halo below (above is +5 implicitly)
#define SXT 44                         // x extent: 32+4+5=41, padded to 44 (11 float4)
#define SYT 17                         // 8+4+5
#define SZT 17
#define NSLOT (SZT * SYT * 11)         // float4 fill slots = 3179

__global__ __launch_bounds__(256) void st3d_kernel(const float* __restrict__ src,
                                                   const float* __restrict__ flow,
                                                   float* __restrict__ out) {
    __shared__ float tile[SZT * SYT * SXT];   // 50,864 B

    const float SZ = (float)D_ / (float)(D_ - 1);
    const float SY = (float)H_ / (float)(H_ - 1);
    const float SX = (float)W_ / (float)(W_ - 1);

    const int bx  = blockIdx.x;              // 0..4
    const int by  = blockIdx.y;              // 0..23
    const int bzb = blockIdx.z;              // 0..39
    const int b   = bzb / (D_ / TZ);
    const int bz  = bzb % (D_ / TZ);

    const int oxi = bx * TX - HLO;
    const int oyi = by * TY - HLO;
    const int ozi = bz * TZ - HLO;

    const float* __restrict__ sp = src + (size_t)b * DHW_;   // C == 1
    const int tid = threadIdx.x;

    // ---- stage src tile into LDS (dense, aligned float4 where possible) ----
    for (int l = tid; l < NSLOT; l += 256) {
        int x4  = l % 11;
        int rem = l / 11;
        int yy  = rem % SYT;
        int zz  = rem / SYT;
        int gz  = min(max(ozi + zz, 0), D_ - 1);
        int gy  = min(max(oyi + yy, 0), H_ - 1);
        int gx0 = oxi + x4 * 4;                  // multiple of 4 -> 16B aligned
        const float* rowp = sp + (size_t)gz * HW_ + (size_t)gy * W_;
        float4 v;
        if (gx0 >= 0 && gx0 <= W_ - 4) {
            v = *(const float4*)(rowp + gx0);
        } else {
            v.x = rowp[min(max(gx0 + 0, 0), W_ - 1)];
            v.y = rowp[min(max(gx0 + 1, 0), W_ - 1)];
            v.z = rowp[min(max(gx0 + 2, 0), W_ - 1)];
            v.w = rowp[min(max(gx0 + 3, 0), W_ - 1)];
        }
        *(float4*)&tile[(zz * SYT + yy) * SXT + x4 * 4] = v;
    }

    // ---- prefetch flow for all 8 z-slices (24 independent loads) ----
    const int lxl = tid % TX;
    const int lyl = tid / TX;                 // 0..7
    const int w = bx * TX + lxl;
    const int h = by * TY + lyl;
    const float* __restrict__ fb = flow + (size_t)b * 3 * DHW_;
    float fza[TZ], fya[TZ], fxa[TZ];
    #pragma unroll
    for (int k = 0; k < TZ; ++k) {
        int d = bz * TZ + k;
        int s = d * HW_ + h * W_ + w;
        fza[k] = fb[s];
        fya[k] = fb[DHW_ + s];
        fxa[k] = fb[2 * DHW_ + s];
    }

    __syncthreads();

    #pragma unroll
    for (int k = 0; k < TZ; ++k) {
        const int d = bz * TZ + k;
        const float z = (d + fza[k]) * SZ - 0.5f;
        const float y = (h + fya[k]) * SY - 0.5f;
        const float x = (w + fxa[k]) * SX - 0.5f;

        const float zf = floorf(z), yf = floorf(y), xf = floorf(x);
        const int z0 = (int)zf, y0 = (int)yf, x0 = (int)xf;
        const int z1 = z0 + 1, y1 = y0 + 1, x1 = x0 + 1;

        float wz1 = z - zf, wy1 = y - yf, wx1 = x - xf;
        float wz0 = 1.0f - wz1, wy0 = 1.0f - wy1, wx0 = 1.0f - wx1;

        // zeros padding folded into weights
        wz0 = ((unsigned)z0 < (unsigned)D_) ? wz0 : 0.0f;
        wz1 = ((unsigned)z1 < (unsigned)D_) ? wz1 : 0.0f;
        wy0 = ((unsigned)y0 < (unsigned)H_) ? wy0 : 0.0f;
        wy1 = ((unsigned)y1 < (unsigned)H_) ? wy1 : 0.0f;
        wx0 = ((unsigned)x0 < (unsigned)W_) ? wx0 : 0.0f;
        wx1 = ((unsigned)x1 < (unsigned)W_) ? wx1 : 0.0f;

        const int z0c = min(max(z0, 0), D_ - 1), z1c = min(max(z1, 0), D_ - 1);
        const int y0c = min(max(y0, 0), H_ - 1), y1c = min(max(y1, 0), H_ - 1);
        const int x0c = min(max(x0, 0), W_ - 1), x1c = min(max(x1, 0), W_ - 1);

        float v000, v001, v010, v011, v100, v101, v110, v111;

        const bool inTile = ((unsigned)(z0c - ozi) <= SZT - 2) &&
                            ((unsigned)(y0c - oyi) <= SYT - 2) &&
                            ((unsigned)(x0c - oxi) <= SXT - 2);
        if (inTile) {
            const int az0 = z0c - ozi, az1 = z1c - ozi;
            const int ay0 = y0c - oyi, ay1 = y1c - oyi;
            const int ax0 = x0c - oxi, ax1 = x1c - oxi;
            const int r00 = (az0 * SYT + ay0) * SXT;
            const int r01 = (az0 * SYT + ay1) * SXT;
            const int r10 = (az1 * SYT + ay0) * SXT;
            const int r11 = (az1 * SYT + ay1) * SXT;
            v000 = tile[r00 + ax0]; v001 = tile[r00 + ax1];
            v010 = tile[r01 + ax0]; v011 = tile[r01 + ax1];
            v100 = tile[r10 + ax0]; v101 = tile[r10 + ax1];
            v110 = tile[r11 + ax0]; v111 = tile[r11 + ax1];
        } else {
            // rare far-flow fallback: exact global gather (clamped)
            const float* p00 = sp + (size_t)z0c * HW_ + (size_t)y0c * W_;
            const float* p01 = sp + (size_t)z0c * HW_ + (size_t)y1c * W_;
            const float* p10 = sp + (size_t)z1c * HW_ + (size_t)y0c * W_;
            const float* p11 = sp + (size_t)z1c * HW_ + (size_t)y1c * W_;
            v000 = p00[x0c]; v001 = p00[x1c];
            v010 = p01[x0c]; v011 = p01[x1c];
            v100 = p10[x0c]; v101 = p10[x1c];
            v110 = p11[x0c]; v111 = p11[x1c];
        }

        const float r = ((v000 * wx0 + v001 * wx1) * wy0 + (v010 * wx0 + v011 * wx1) * wy1) * wz0
                      + ((v100 * wx0 + v101 * wx1) * wy0 + (v110 * wx0 + v111 * wx1) * wy1) * wz1;

        out[(size_t)b * DHW_ + (size_t)d * HW_ + (size_t)h * W_ + w] = r;
    }
}

extern "C" void kernel_launch(void* const* d_in, const int* in_sizes, int n_in,
                              void* d_out, int out_size, void* d_ws, size_t ws_size,
                              hipStream_t stream) {
    const float* src  = (const float*)d_in[0];
    const float* flow = (const float*)d_in[1];
    float* out = (float*)d_out;

    dim3 grid(W_ / TX, H_ / TY, (D_ / TZ) * B_);   // 5 x 24 x 40 = 4800 blocks
    st3d_kernel<<<grid, dim3(256), 0, stream>>>(src, flow, out);
}

// Round 4
// 222.441 us; speedup vs baseline: 1.4235x; 1.1439x over previous
//
#include <hip/hip_runtime.h>

// Problem constants (from reference setup_inputs)
#define B_ 2
#define D_ 160
#define H_ 192
#define W_ 160

constexpr int HW_  = H_ * W_;          // 30720
constexpr int DHW_ = D_ * HW_;         // 4915200

// Output tile per block (256 threads, 8 voxels/thread along z)
#define TX 32
#define TY 8
#define TZ 8
#define HLO 4                          // halo below (above is +5 implicitly)
#define SXT 44                         // 32+4+5=41 padded to 44 (11 float4)
#define SYT 17                         // 8+4+5
#define SZT 17
#define NSLOT (SZT * SYT * 11)         // 3179 float4 slots
#define NITER 13                       // ceil(NSLOT/256)
#define TAILN (NSLOT - 256 * (NITER - 1))   // 107

// Async global->LDS DMA, 16B per lane. LDS dst must be lane-linear (it is:
// slot l lives at byte offset l*16, and lane L of a wave handles slot base+L).
__device__ __forceinline__ void gload_lds16(const float* g, float* l) {
    __builtin_amdgcn_global_load_lds(
        (const __attribute__((address_space(1))) unsigned int*)g,
        (__attribute__((address_space(3))) unsigned int*)l,
        16, 0, 0);
}

// Exact fallback for far-flow voxels: clamped global gather + zero-pad weights.
__device__ __forceinline__ float sample_global(const float* __restrict__ sp,
                                               float z, float y, float x) {
    const float zf = floorf(z), yf = floorf(y), xf = floorf(x);
    const int z0 = (int)zf, y0 = (int)yf, x0 = (int)xf;
    const int z1 = z0 + 1, y1 = y0 + 1, x1 = x0 + 1;
    float wz1 = z - zf, wy1 = y - yf, wx1 = x - xf;
    float wz0 = 1.f - wz1, wy0 = 1.f - wy1, wx0 = 1.f - wx1;
    wz0 = ((unsigned)z0 < (unsigned)D_) ? wz0 : 0.f;
    wz1 = ((unsigned)z1 < (unsigned)D_) ? wz1 : 0.f;
    wy0 = ((unsigned)y0 < (unsigned)H_) ? wy0 : 0.f;
    wy1 = ((unsigned)y1 < (unsigned)H_) ? wy1 : 0.f;
    wx0 = ((unsigned)x0 < (unsigned)W_) ? wx0 : 0.f;
    wx1 = ((unsigned)x1 < (unsigned)W_) ? wx1 : 0.f;
    const int z0c = min(max(z0, 0), D_ - 1), z1c = min(max(z1, 0), D_ - 1);
    const int y0c = min(max(y0, 0), H_ - 1), y1c = min(max(y1, 0), H_ - 1);
    const int x0c = min(max(x0, 0), W_ - 1), x1c = min(max(x1, 0), W_ - 1);
    const float* p00 = sp + (size_t)z0c * HW_ + (size_t)y0c * W_;
    const float* p01 = sp + (size_t)z0c * HW_ + (size_t)y1c * W_;
    const float* p10 = sp + (size_t)z1c * HW_ + (size_t)y0c * W_;
    const float* p11 = sp + (size_t)z1c * HW_ + (size_t)y1c * W_;
    const float v000 = p00[x0c], v001 = p00[x1c];
    const float v010 = p01[x0c], v011 = p01[x1c];
    const float v100 = p10[x0c], v101 = p10[x1c];
    const float v110 = p11[x0c], v111 = p11[x1c];
    return ((v000 * wx0 + v001 * wx1) * wy0 + (v010 * wx0 + v011 * wx1) * wy1) * wz0
         + ((v100 * wx0 + v101 * wx1) * wy0 + (v110 * wx0 + v111 * wx1) * wy1) * wz1;
}

__global__ __launch_bounds__(256) void st3d_kernel(const float* __restrict__ src,
                                                   const float* __restrict__ flow,
                                                   float* __restrict__ out) {
    __shared__ float tile[SZT * SYT * SXT];   // 50,864 B -> 3 blocks/CU

    const float SZf = (float)D_ / (float)(D_ - 1);
    const float SYf = (float)H_ / (float)(H_ - 1);
    const float SXf = (float)W_ / (float)(W_ - 1);

    const int tid = threadIdx.x;
    const int bx = blockIdx.x, by = blockIdx.y, bzb = blockIdx.z;
    const int b  = bzb / (D_ / TZ);
    const int bz = bzb % (D_ / TZ);

    const int oxi = bx * TX - HLO;
    const int oyi = by * TY - HLO;
    const int ozi = bz * TZ - HLO;

    const float* __restrict__ sp = src + (size_t)b * DHW_;   // C == 1
    // tile entirely inside the volume?
    const bool interior = (bx >= 1) & (bx <= 3) & (by >= 1) & (by <= 22) & (bz >= 1) & (bz <= 18);

    // slot l = x4 + 11*yy + 187*zz ; thread handles l = tid + 256*i
    const int r0 = tid / 11;
    int x4 = tid - r0 * 11;
    int yy = r0 % 17;
    int zz = r0 / 17;

    if (interior) {
        const float* gbase = sp + (size_t)ozi * HW_ + oyi * W_ + oxi;  // 16B-aligned rows
        #pragma unroll
        for (int i = 0; i < NITER; ++i) {
            if (i < NITER - 1 || tid < TAILN) {
                gload_lds16(gbase + zz * HW_ + yy * W_ + 4 * x4,
                            &tile[4 * (tid + 256 * i)]);
            }
            // l += 256  ==  x4+=3 (carry), yy+=6 (carry), zz+=1
            x4 += 3; if (x4 >= 11) { x4 -= 11; yy += 1; }
            yy += 6; zz += 1; if (yy >= 17) { yy -= 17; zz += 1; }
        }
    } else {
        float4 v[NITER];
        int x4b = x4, yyb = yy, zzb = zz;
        #pragma unroll
        for (int i = 0; i < NITER; ++i) {            // batched: all loads in flight
            if (i < NITER - 1 || tid < TAILN) {
                const int gz = min(max(ozi + zzb, 0), D_ - 1);
                const int gy = min(max(oyi + yyb, 0), H_ - 1);
                const int gx0 = oxi + 4 * x4b;
                const float* rowp = sp + (size_t)gz * HW_ + (size_t)gy * W_;
                if (gx0 >= 0 && gx0 <= W_ - 4) {
                    v[i] = *(const float4*)(rowp + gx0);
                } else {
                    v[i].x = rowp[min(max(gx0 + 0, 0), W_ - 1)];
                    v[i].y = rowp[min(max(gx0 + 1, 0), W_ - 1)];
                    v[i].z = rowp[min(max(gx0 + 2, 0), W_ - 1)];
                    v[i].w = rowp[min(max(gx0 + 3, 0), W_ - 1)];
                }
            }
            x4b += 3; if (x4b >= 11) { x4b -= 11; yyb += 1; }
            yyb += 6; zzb += 1; if (yyb >= 17) { yyb -= 17; zzb += 1; }
        }
        #pragma unroll
        for (int i = 0; i < NITER; ++i) {
            if (i < NITER - 1 || tid < TAILN)
                *(float4*)&tile[4 * (tid + 256 * i)] = v[i];
        }
    }

    // flow prefetch: 24 independent coalesced loads, overlap the staging drain
    const int lxl = tid & (TX - 1);
    const int lyl = tid >> 5;
    const int w = bx * TX + lxl;
    const int h = by * TY + lyl;
    const float* __restrict__ fb = flow + (size_t)b * 3 * DHW_;
    const int s0 = (bz * TZ) * HW_ + h * W_ + w;
    float fza[TZ], fya[TZ], fxa[TZ];
    #pragma unroll
    for (int k = 0; k < TZ; ++k) {
        fza[k] = fb[s0 + k * HW_];
        fya[k] = fb[DHW_ + s0 + k * HW_];
        fxa[k] = fb[2 * DHW_ + s0 + k * HW_];
    }

    __syncthreads();

    const float c_y = h * SYf - 0.5f;
    const float c_x = w * SXf - 0.5f;
    const size_t obase = (size_t)b * DHW_ + (size_t)s0;

    if (interior) {
        #pragma unroll
        for (int k = 0; k < TZ; ++k) {
            const int d = bz * TZ + k;
            const float z = fmaf(fza[k], SZf, d * SZf - 0.5f);
            const float y = fmaf(fya[k], SYf, c_y);
            const float x = fmaf(fxa[k], SXf, c_x);
            const float zf = floorf(z), yf = floorf(y), xf = floorf(x);
            const int az0 = (int)zf - ozi;
            const int ay0 = (int)yf - oyi;
            const int ax0 = (int)xf - oxi;
            float r;
            if (((unsigned)az0 <= SZT - 2) & ((unsigned)ay0 <= SYT - 2) & ((unsigned)ax0 <= SXT - 2)) {
                const float tz = z - zf, ty = y - yf, tx = x - xf;
                const int idx = (az0 * SYT + ay0) * SXT + ax0;   // one base, 7 imm offsets
                const float v000 = tile[idx],                 v001 = tile[idx + 1];
                const float v010 = tile[idx + SXT],           v011 = tile[idx + SXT + 1];
                const float v100 = tile[idx + SYT * SXT],     v101 = tile[idx + SYT * SXT + 1];
                const float v110 = tile[idx + SYT * SXT + SXT], v111 = tile[idx + SYT * SXT + SXT + 1];
                const float a0 = v000 + tx * (v001 - v000);
                const float a1 = v010 + tx * (v011 - v010);
                const float a2 = v100 + tx * (v101 - v100);
                const float a3 = v110 + tx * (v111 - v110);
                const float b0 = a0 + ty * (a1 - a0);
                const float b1 = a2 + ty * (a3 - a2);
                r = b0 + tz * (b1 - b0);
            } else {
                r = sample_global(sp, z, y, x);   // rare (~0.2% of voxels)
            }
            out[obase + (size_t)k * HW_] = r;
        }
    } else {
        #pragma unroll
        for (int k = 0; k < TZ; ++k) {
            const int d = bz * TZ + k;
            const float z = fmaf(fza[k], SZf, d * SZf - 0.5f);
            const float y = fmaf(fya[k], SYf, c_y);
            const float x = fmaf(fxa[k], SXf, c_x);
            const float zf = floorf(z), yf = floorf(y), xf = floorf(x);
            const int z0 = (int)zf, y0 = (int)yf, x0 = (int)xf;
            const int z1 = z0 + 1, y1 = y0 + 1, x1 = x0 + 1;
            float wz1 = z - zf, wy1 = y - yf, wx1 = x - xf;
            float wz0 = 1.f - wz1, wy0 = 1.f - wy1, wx0 = 1.f - wx1;
            wz0 = ((unsigned)z0 < (unsigned)D_) ? wz0 : 0.f;
            wz1 = ((unsigned)z1 < (unsigned)D_) ? wz1 : 0.f;
            wy0 = ((unsigned)y0 < (unsigned)H_) ? wy0 : 0.f;
            wy1 = ((unsigned)y1 < (unsigned)H_) ? wy1 : 0.f;
            wx0 = ((unsigned)x0 < (unsigned)W_) ? wx0 : 0.f;
            wx1 = ((unsigned)x1 < (unsigned)W_) ? wx1 : 0.f;
            const int z0c = min(max(z0, 0), D_ - 1), z1c = min(max(z1, 0), D_ - 1);
            const int y0c = min(max(y0, 0), H_ - 1), y1c = min(max(y1, 0), H_ - 1);
            const int x0c = min(max(x0, 0), W_ - 1), x1c = min(max(x1, 0), W_ - 1);
            float r;
            const bool inTile = ((unsigned)(z0c - ozi) <= SZT - 2) &&
                                ((unsigned)(y0c - oyi) <= SYT - 2) &&
                                ((unsigned)(x0c - oxi) <= SXT - 2);
            if (inTile) {
                const int az0 = z0c - ozi, az1 = z1c - ozi;
                const int ay0 = y0c - oyi, ay1 = y1c - oyi;
                const int ax0 = x0c - oxi, ax1 = x1c - oxi;
                const int q00 = (az0 * SYT + ay0) * SXT;
                const int q01 = (az0 * SYT + ay1) * SXT;
                const int q10 = (az1 * SYT + ay0) * SXT;
                const int q11 = (az1 * SYT + ay1) * SXT;
                const float v000 = tile[q00 + ax0], v001 = tile[q00 + ax1];
                const float v010 = tile[q01 + ax0], v011 = tile[q01 + ax1];
                const float v100 = tile[q10 + ax0], v101 = tile[q10 + ax1];
                const float v110 = tile[q11 + ax0], v111 = tile[q11 + ax1];
                r = ((v000 * wx0 + v001 * wx1) * wy0 + (v010 * wx0 + v011 * wx1) * wy1) * wz0
                  + ((v100 * wx0 + v101 * wx1) * wy0 + (v110 * wx0 + v111 * wx1) * wy1) * wz1;
            } else {
                const float* p00 = sp + (size_t)z0c * HW_ + (size_t)y0c * W_;
                const float* p01 = sp + (size_t)z0c * HW_ + (size_t)y1c * W_;
                const float* p10 = sp + (size_t)z1c * HW_ + (size_t)y0c * W_;
                const float* p11 = sp + (size_t)z1c * HW_ + (size_t)y1c * W_;
                const float v000 = p00[x0c], v001 = p00[x1c];
                const float v010 = p01[x0c], v011 = p01[x1c];
                const float v100 = p10[x0c], v101 = p10[x1c];
                const float v110 = p11[x0c], v111 = p11[x1c];
                r = ((v000 * wx0 + v001 * wx1) * wy0 + (v010 * wx0 + v011 * wx1) * wy1) * wz0
                  + ((v100 * wx0 + v101 * wx1) * wy0 + (v110 * wx0 + v111 * wx1) * wy1) * wz1;
            }
            out[obase + (size_t)k * HW_] = r;
        }
    }
}

extern "C" void kernel_launch(void* const* d_in, const int* in_sizes, int n_in,
                              void* d_out, int out_size, void* d_ws, size_t ws_size,
                              hipStream_t stream) {
    const float* src  = (const float*)d_in[0];
    const float* flow = (const float*)d_in[1];
    float* out = (float*)d_out;

    dim3 grid(W_ / TX, H_ / TY, (D_ / TZ) * B_);   // 5 x 24 x 40 = 4800 blocks
    st3d_kernel<<<grid, dim3(256), 0, stream>>>(src, flow, out);
}

// Round 5
// 217.830 us; speedup vs baseline: 1.4537x; 1.0212x over previous
//
#include <hip/hip_runtime.h>

// Problem constants (from reference setup_inputs)
#define B_ 2
#define D_ 160
#define H_ 192
#define W_ 160

constexpr int HW_  = H_ * W_;          // 30720
constexpr int DHW_ = D_ * HW_;         // 4915200

// Output tile per block (256 threads, 8 voxels/thread along z)
#define TX 32
#define TY 8
#define TZ 8
// Asymmetric halos: x [-4,+3] (keeps 16B-aligned DMA source), y [-3,+4], z [-3,+3]
#define HX 4
#define HY 3
#define HZ 3
#define SXT 40                         // 32+4+3=39 -> pad 40 (10 float4 slots)
#define SYT 16                         // 8+3+4
#define SZT 15                         // 8+3+3
#define NSLOT (SZT * SYT * 10)         // 2400 float4 slots
#define NITER 10                       // ceil(2400/256)
#define TAILN (NSLOT - 256 * (NITER - 1))   // 96

// Async global->LDS DMA, 16B per lane. LDS dst is lane-linear (slot l at byte
// offset l*16; lane L of a wave handles slot base+L).
__device__ __forceinline__ void gload_lds16(const float* g, float* l) {
    __builtin_amdgcn_global_load_lds(
        (const __attribute__((address_space(1))) unsigned int*)g,
        (__attribute__((address_space(3))) unsigned int*)l,
        16, 0, 0);
}

// Exact fallback for far-flow voxels: clamped global gather + zero-pad weights.
__device__ __forceinline__ float sample_global(const float* __restrict__ sp,
                                               float z, float y, float x) {
    const float zf = floorf(z), yf = floorf(y), xf = floorf(x);
    const int z0 = (int)zf, y0 = (int)yf, x0 = (int)xf;
    const int z1 = z0 + 1, y1 = y0 + 1, x1 = x0 + 1;
    float wz1 = z - zf, wy1 = y - yf, wx1 = x - xf;
    float wz0 = 1.f - wz1, wy0 = 1.f - wy1, wx0 = 1.f - wx1;
    wz0 = ((unsigned)z0 < (unsigned)D_) ? wz0 : 0.f;
    wz1 = ((unsigned)z1 < (unsigned)D_) ? wz1 : 0.f;
    wy0 = ((unsigned)y0 < (unsigned)H_) ? wy0 : 0.f;
    wy1 = ((unsigned)y1 < (unsigned)H_) ? wy1 : 0.f;
    wx0 = ((unsigned)x0 < (unsigned)W_) ? wx0 : 0.f;
    wx1 = ((unsigned)x1 < (unsigned)W_) ? wx1 : 0.f;
    const int z0c = min(max(z0, 0), D_ - 1), z1c = min(max(z1, 0), D_ - 1);
    const int y0c = min(max(y0, 0), H_ - 1), y1c = min(max(y1, 0), H_ - 1);
    const int x0c = min(max(x0, 0), W_ - 1), x1c = min(max(x1, 0), W_ - 1);
    const float* p00 = sp + (size_t)z0c * HW_ + (size_t)y0c * W_;
    const float* p01 = sp + (size_t)z0c * HW_ + (size_t)y1c * W_;
    const float* p10 = sp + (size_t)z1c * HW_ + (size_t)y0c * W_;
    const float* p11 = sp + (size_t)z1c * HW_ + (size_t)y1c * W_;
    const float v000 = p00[x0c], v001 = p00[x1c];
    const float v010 = p01[x0c], v011 = p01[x1c];
    const float v100 = p10[x0c], v101 = p10[x1c];
    const float v110 = p11[x0c], v111 = p11[x1c];
    return ((v000 * wx0 + v001 * wx1) * wy0 + (v010 * wx0 + v011 * wx1) * wy1) * wz0
         + ((v100 * wx0 + v101 * wx1) * wy0 + (v110 * wx0 + v111 * wx1) * wy1) * wz1;
}

__global__ __launch_bounds__(256) void st3d_kernel(const float* __restrict__ src,
                                                   const float* __restrict__ flow,
                                                   float* __restrict__ out) {
    __shared__ float tile[SZT * SYT * SXT];   // 38,400 B -> 4 blocks/CU (16 waves)

    const float SZf = (float)D_ / (float)(D_ - 1);
    const float SYf = (float)H_ / (float)(H_ - 1);
    const float SXf = (float)W_ / (float)(W_ - 1);

    const int tid = threadIdx.x;
    const int bx = blockIdx.x, by = blockIdx.y, bzb = blockIdx.z;
    const int b  = bzb / (D_ / TZ);
    const int bz = bzb % (D_ / TZ);

    const int oxi = bx * TX - HX;      // multiple of 4 -> DMA source stays 16B aligned
    const int oyi = by * TY - HY;
    const int ozi = bz * TZ - HZ;

    const float* __restrict__ sp = src + (size_t)b * DHW_;   // C == 1
    const bool interior = (bx >= 1) & (bx <= 3) & (by >= 1) & (by <= 22) & (bz >= 1) & (bz <= 18);

    // ---- flow prefetch FIRST (24 independent coalesced loads; the single
    //      barrier drain then covers both these and the staging DMAs) ----
    const int lxl = tid & (TX - 1);
    const int lyl = tid >> 5;
    const int w = bx * TX + lxl;
    const int h = by * TY + lyl;
    const float* __restrict__ fb = flow + (size_t)b * 3 * DHW_;
    const int s0 = (bz * TZ) * HW_ + h * W_ + w;
    float fza[TZ], fya[TZ], fxa[TZ];
    #pragma unroll
    for (int k = 0; k < TZ; ++k) {
        fza[k] = fb[s0 + k * HW_];
        fya[k] = fb[DHW_ + s0 + k * HW_];
        fxa[k] = fb[2 * DHW_ + s0 + k * HW_];
    }

    // slot l = x4 + 10*yy + 160*zz ; thread handles l = tid + 256*i
    const int r0 = tid / 10;
    int x4 = tid - r0 * 10;
    int yy = r0 & 15;
    int zz = r0 >> 4;

    if (interior) {
        const float* gbase = sp + (size_t)ozi * HW_ + oyi * W_ + oxi;
        #pragma unroll
        for (int i = 0; i < NITER; ++i) {
            if (i < NITER - 1 || tid < TAILN) {
                gload_lds16(gbase + zz * HW_ + yy * W_ + 4 * x4,
                            &tile[4 * (tid + 256 * i)]);
            }
            // l += 256 == x4 += 6 (carry), yy += 9, zz += 1 (then carry)
            x4 += 6; if (x4 >= 10) { x4 -= 10; yy += 1; }
            yy += 9; zz += 1; if (yy >= 16) { yy -= 16; zz += 1; }
        }
    } else {
        float4 v[NITER];
        int x4b = x4, yyb = yy, zzb = zz;
        #pragma unroll
        for (int i = 0; i < NITER; ++i) {            // batched: all loads in flight
            if (i < NITER - 1 || tid < TAILN) {
                const int gz = min(max(ozi + zzb, 0), D_ - 1);
                const int gy = min(max(oyi + yyb, 0), H_ - 1);
                const int gx0 = oxi + 4 * x4b;
                const float* rowp = sp + (size_t)gz * HW_ + (size_t)gy * W_;
                if (gx0 >= 0 && gx0 <= W_ - 4) {
                    v[i] = *(const float4*)(rowp + gx0);
                } else {
                    v[i].x = rowp[min(max(gx0 + 0, 0), W_ - 1)];
                    v[i].y = rowp[min(max(gx0 + 1, 0), W_ - 1)];
                    v[i].z = rowp[min(max(gx0 + 2, 0), W_ - 1)];
                    v[i].w = rowp[min(max(gx0 + 3, 0), W_ - 1)];
                }
            }
            x4b += 6; if (x4b >= 10) { x4b -= 10; yyb += 1; }
            yyb += 9; zzb += 1; if (yyb >= 16) { yyb -= 16; zzb += 1; }
        }
        #pragma unroll
        for (int i = 0; i < NITER; ++i) {
            if (i < NITER - 1 || tid < TAILN)
                *(float4*)&tile[4 * (tid + 256 * i)] = v[i];
        }
    }

    __syncthreads();

    const float c_y = h * SYf - 0.5f;
    const float c_x = w * SXf - 0.5f;
    const size_t obase = (size_t)b * DHW_ + (size_t)s0;

    if (interior) {
        #pragma unroll
        for (int k = 0; k < TZ; ++k) {
            const int d = bz * TZ + k;
            const float z = fmaf(fza[k], SZf, d * SZf - 0.5f);
            const float y = fmaf(fya[k], SYf, c_y);
            const float x = fmaf(fxa[k], SXf, c_x);
            const float zf = floorf(z), yf = floorf(y), xf = floorf(x);
            const int az0 = (int)zf - ozi;
            const int ay0 = (int)yf - oyi;
            const int ax0 = (int)xf - oxi;
            float r;
            if (((unsigned)az0 <= SZT - 2) & ((unsigned)ay0 <= SYT - 2) & ((unsigned)ax0 <= SXT - 2)) {
                const float tz = z - zf, ty = y - yf, tx = x - xf;
                const int idx = (az0 * SYT + ay0) * SXT + ax0;   // one base, 7 imm offsets
                const float v000 = tile[idx],                     v001 = tile[idx + 1];
                const float v010 = tile[idx + SXT],               v011 = tile[idx + SXT + 1];
                const float v100 = tile[idx + SYT * SXT],         v101 = tile[idx + SYT * SXT + 1];
                const float v110 = tile[idx + SYT * SXT + SXT],   v111 = tile[idx + SYT * SXT + SXT + 1];
                const float a0 = v000 + tx * (v001 - v000);
                const float a1 = v010 + tx * (v011 - v010);
                const float a2 = v100 + tx * (v101 - v100);
                const float a3 = v110 + tx * (v111 - v110);
                const float b0 = a0 + ty * (a1 - a0);
                const float b1 = a2 + ty * (a3 - a2);
                r = b0 + tz * (b1 - b0);
            } else {
                r = sample_global(sp, z, y, x);   // rare far-flow fallback
            }
            out[obase + (size_t)k * HW_] = r;
        }
    } else {
        #pragma unroll
        for (int k = 0; k < TZ; ++k) {
            const int d = bz * TZ + k;
            const float z = fmaf(fza[k], SZf, d * SZf - 0.5f);
            const float y = fmaf(fya[k], SYf, c_y);
            const float x = fmaf(fxa[k], SXf, c_x);
            const float zf = floorf(z), yf = floorf(y), xf = floorf(x);
            const int z0 = (int)zf, y0 = (int)yf, x0 = (int)xf;
            const int z1 = z0 + 1, y1 = y0 + 1, x1 = x0 + 1;
            float wz1 = z - zf, wy1 = y - yf, wx1 = x - xf;
            float wz0 = 1.f - wz1, wy0 = 1.f - wy1, wx0 = 1.f - wx1;
            wz0 = ((unsigned)z0 < (unsigned)D_) ? wz0 : 0.f;
            wz1 = ((unsigned)z1 < (unsigned)D_) ? wz1 : 0.f;
            wy0 = ((unsigned)y0 < (unsigned)H_) ? wy0 : 0.f;
            wy1 = ((unsigned)y1 < (unsigned)H_) ? wy1 : 0.f;
            wx0 = ((unsigned)x0 < (unsigned)W_) ? wx0 : 0.f;
            wx1 = ((unsigned)x1 < (unsigned)W_) ? wx1 : 0.f;
            const int z0c = min(max(z0, 0), D_ - 1), z1c = min(max(z1, 0), D_ - 1);
            const int y0c = min(max(y0, 0), H_ - 1), y1c = min(max(y1, 0), H_ - 1);
            const int x0c = min(max(x0, 0), W_ - 1), x1c = min(max(x1, 0), W_ - 1);
            float r;
            const bool inTile = ((unsigned)(z0c - ozi) <= SZT - 2) &&
                                ((unsigned)(y0c - oyi) <= SYT - 2) &&
                                ((unsigned)(x0c - oxi) <= SXT - 2);
            if (inTile) {
                const int az0 = z0c - ozi, az1 = z1c - ozi;
                const int ay0 = y0c - oyi, ay1 = y1c - oyi;
                const int ax0 = x0c - oxi, ax1 = x1c - oxi;
                const int q00 = (az0 * SYT + ay0) * SXT;
                const int q01 = (az0 * SYT + ay1) * SXT;
                const int q10 = (az1 * SYT + ay0) * SXT;
                const int q11 = (az1 * SYT + ay1) * SXT;
                const float v000 = tile[q00 + ax0], v001 = tile[q00 + ax1];
                const float v010 = tile[q01 + ax0], v011 = tile[q01 + ax1];
                const float v100 = tile[q10 + ax0], v101 = tile[q10 + ax1];
                const float v110 = tile[q11 + ax0], v111 = tile[q11 + ax1];
                r = ((v000 * wx0 + v001 * wx1) * wy0 + (v010 * wx0 + v011 * wx1) * wy1) * wz0
                  + ((v100 * wx0 + v101 * wx1) * wy0 + (v110 * wx0 + v111 * wx1) * wy1) * wz1;
            } else {
                const float* p00 = sp + (size_t)z0c * HW_ + (size_t)y0c * W_;
                const float* p01 = sp + (size_t)z0c * HW_ + (size_t)y1c * W_;
                const float* p10 = sp + (size_t)z1c * HW_ + (size_t)y0c * W_;
                const float* p11 = sp + (size_t)z1c * HW_ + (size_t)y1c * W_;
                const float v000 = p00[x0c], v001 = p00[x1c];
                const float v010 = p01[x0c], v011 = p01[x1c];
                const float v100 = p10[x0c], v101 = p10[x1c];
                const float v110 = p11[x0c], v111 = p11[x1c];
                r = ((v000 * wx0 + v001 * wx1) * wy0 + (v010 * wx0 + v011 * wx1) * wy1) * wz0
                  + ((v100 * wx0 + v101 * wx1) * wy0 + (v110 * wx0 + v111 * wx1) * wy1) * wz1;
            }
            out[obase + (size_t)k * HW_] = r;
        }
    }
}

extern "C" void kernel_launch(void* const* d_in, const int* in_sizes, int n_in,
                              void* d_out, int out_size, void* d_ws, size_t ws_size,
                              hipStream_t stream) {
    const float* src  = (const float*)d_in[0];
    const float* flow = (const float*)d_in[1];
    float* out = (float*)d_out;

    dim3 grid(W_ / TX, H_ / TY, (D_ / TZ) * B_);   // 5 x 24 x 40 = 4800 blocks
    st3d_kernel<<<grid, dim3(256), 0, stream>>>(src, flow, out);
}